// Round 1
// baseline (385.413 us; speedup 1.0000x reference)
//
#include <hip/hip_runtime.h>

// GCN aggregation: out = A @ embeds, A in COO (row sorted), N=100000, E=1.6M, D=64.
// One wave (64 lanes) processes EDGES_PER_WAVE contiguous edges; lane d owns dim d.
// Sorted rows => register accumulation, flush on row change. Atomics only at
// chunk-boundary rows (first row + final flush of each wave's chunk).

#define GCN_D 64
#define EDGES_PER_WAVE 256

__global__ __launch_bounds__(256) void gcn_spmm_kernel(
    const int* __restrict__ edge_row,
    const int* __restrict__ edge_col,
    const float* __restrict__ edge_val,
    const float* __restrict__ embeds,
    float* __restrict__ out,
    int E)
{
    const int wave = (blockIdx.x * blockDim.x + threadIdx.x) >> 6;
    const int lane = threadIdx.x & 63;

    int start = wave * EDGES_PER_WAVE;
    if (start >= E) return;
    int end = start + EDGES_PER_WAVE;
    if (end > E) end = E;

    // Force wave-uniform loop bounds so edge metadata loads become scalar.
    start = __builtin_amdgcn_readfirstlane(start);
    end   = __builtin_amdgcn_readfirstlane(end);

    const int first_row = edge_row[start];
    int cur = first_row;
    float acc = 0.0f;

    for (int e = start; e < end; ++e) {
        const int   r = edge_row[e];
        const int   c = edge_col[e];
        const float v = edge_val[e];
        if (r != cur) {
            // flush accumulated row
            float* dst = out + (size_t)cur * GCN_D + lane;
            if (cur == first_row) {
                atomicAdd(dst, acc);   // may be shared with previous chunk
            } else {
                *dst = acc;            // interior row: exclusively ours
            }
            acc = 0.0f;
            cur = r;
        }
        acc += v * embeds[(size_t)c * GCN_D + lane];
    }
    // Final row may continue into the next chunk (or be the first row too).
    atomicAdd(out + (size_t)cur * GCN_D + lane, acc);
}

extern "C" void kernel_launch(void* const* d_in, const int* in_sizes, int n_in,
                              void* d_out, int out_size, void* d_ws, size_t ws_size,
                              hipStream_t stream) {
    const int*   edge_row = (const int*)d_in[0];
    const int*   edge_col = (const int*)d_in[1];
    const float* edge_val = (const float*)d_in[2];
    const float* embeds   = (const float*)d_in[3];
    float*       out      = (float*)d_out;

    const int E = in_sizes[0];

    // Zero the output (harness poisons it with 0xAA before every timed call).
    hipMemsetAsync(d_out, 0, (size_t)out_size * sizeof(float), stream);

    const int waves  = (E + EDGES_PER_WAVE - 1) / EDGES_PER_WAVE;
    const int blocks = (waves + 3) / 4;   // 4 waves per 256-thread block
    gcn_spmm_kernel<<<blocks, 256, 0, stream>>>(edge_row, edge_col, edge_val,
                                                embeds, out, E);
}

// Round 2
// 163.031 us; speedup vs baseline: 2.3640x; 2.3640x over previous
//
#include <hip/hip_runtime.h>

// GCN aggregation: out = A @ embeds, A in COO (row sorted), N=100000, E=1.6M, D=64.
// One wave (64 lanes) processes EPW contiguous edges; lane d owns dim d.
// Inner loop batches G=8 independent embed gathers per iteration so each wave
// keeps 8 VMEM loads in flight (latency hiding). Row transitions are
// wave-uniform scalar branches. Atomics only at chunk-boundary rows.

#define GCN_D 64
#define EPW   128   // edges per wave
#define G     8     // gather batch (must divide EPW)

__global__ __launch_bounds__(256) void gcn_spmm_kernel(
    const int* __restrict__ edge_row,
    const int* __restrict__ edge_col,
    const float* __restrict__ edge_val,
    const float* __restrict__ embeds,
    float* __restrict__ out,
    int E)
{
    const int wave = (blockIdx.x * blockDim.x + threadIdx.x) >> 6;
    const int lane = threadIdx.x & 63;

    int start = wave * EPW;
    if (start >= E) return;
    int end = start + EPW;
    if (end > E) end = E;

    // Wave-uniform bounds -> edge metadata loads become scalar (s_load).
    start = __builtin_amdgcn_readfirstlane(start);
    end   = __builtin_amdgcn_readfirstlane(end);

    const int first_row = edge_row[start];
    int   cur = first_row;
    float acc = 0.0f;

    int e = start;
    const int full_end = start + ((end - start) / G) * G;

    for (; e < full_end; e += G) {
        int   r[G], c[G];
        float v[G], g[G];

        #pragma unroll
        for (int j = 0; j < G; ++j) {
            r[j] = edge_row[e + j];
            c[j] = edge_col[e + j];
            v[j] = edge_val[e + j];
        }
        // Issue all G independent gathers before consuming any.
        #pragma unroll
        for (int j = 0; j < G; ++j)
            g[j] = embeds[(size_t)c[j] * GCN_D + lane];

        #pragma unroll
        for (int j = 0; j < G; ++j) {
            if (r[j] != cur) {
                float* dst = out + (size_t)cur * GCN_D + lane;
                if (cur == first_row) atomicAdd(dst, acc);  // shared with prev chunk
                else                  *dst = acc;           // interior row: ours alone
                acc = 0.0f;
                cur = r[j];
            }
            acc += v[j] * g[j];
        }
    }
    // Scalar tail (only if E % G != 0 for the last chunk).
    for (; e < end; ++e) {
        const int r = edge_row[e];
        if (r != cur) {
            float* dst = out + (size_t)cur * GCN_D + lane;
            if (cur == first_row) atomicAdd(dst, acc);
            else                  *dst = acc;
            acc = 0.0f;
            cur = r;
        }
        acc += edge_val[e] * embeds[(size_t)edge_col[e] * GCN_D + lane];
    }
    // Final row may continue into the next chunk (or be the first row too).
    atomicAdd(out + (size_t)cur * GCN_D + lane, acc);
}

extern "C" void kernel_launch(void* const* d_in, const int* in_sizes, int n_in,
                              void* d_out, int out_size, void* d_ws, size_t ws_size,
                              hipStream_t stream) {
    const int*   edge_row = (const int*)d_in[0];
    const int*   edge_col = (const int*)d_in[1];
    const float* edge_val = (const float*)d_in[2];
    const float* embeds   = (const float*)d_in[3];
    float*       out      = (float*)d_out;

    const int E = in_sizes[0];

    // Zero the output (harness poisons it with 0xAA before every timed call).
    hipMemsetAsync(d_out, 0, (size_t)out_size * sizeof(float), stream);

    const int waves  = (E + EPW - 1) / EPW;
    const int blocks = (waves + 3) / 4;   // 4 waves per 256-thread block
    gcn_spmm_kernel<<<blocks, 256, 0, stream>>>(edge_row, edge_col, edge_val,
                                                embeds, out, E);
}

// Round 3
// 144.202 us; speedup vs baseline: 2.6727x; 1.1306x over previous
//
#include <hip/hip_runtime.h>

// GCN aggregation: out = A @ embeds, A in COO with SORTED rows.
// N=100000, E=1.6M, D=64.
//
// Pass 1: build row_ptr[N+1] in d_ws from the sorted edge_row.
// Pass 2: one wave per output row. 4 sub-groups of 16 lanes; each sub-group
//         owns a float4 slice of the 64-dim row (16 B/lane) and walks every
//         4th edge, 2 edges per iteration -> up to 8 independent 1KB gathers
//         in flight per wave. Cross-sub reduction via shfl_xor(16|32); one
//         plain float4 store per row (no atomics, no pre-zero: empty rows
//         store 0, which also covers the 0xAA-poisoned d_out).

#define GCN_D 64

__global__ __launch_bounds__(256) void build_row_ptr_kernel(
    const int* __restrict__ edge_row, int* __restrict__ row_ptr, int E, int N)
{
    const int e = blockIdx.x * blockDim.x + threadIdx.x;
    if (e >= E) return;
    const int r    = edge_row[e];
    const int prev = (e == 0) ? -1 : edge_row[e - 1];
    for (int k = prev + 1; k <= r; ++k) row_ptr[k] = e;   // gaps incl. own start
    if (e == E - 1)
        for (int k = r + 1; k <= N; ++k) row_ptr[k] = E;  // tail sentinel
}

__global__ __launch_bounds__(256) void gcn_row_kernel(
    const int* __restrict__ row_ptr,
    const int* __restrict__ edge_col,
    const float* __restrict__ edge_val,
    const float* __restrict__ embeds,
    float* __restrict__ out,
    int N)
{
    const int row = (blockIdx.x * blockDim.x + threadIdx.x) >> 6;
    if (row >= N) return;
    const int lane = threadIdx.x & 63;
    const int sub  = lane >> 4;          // 0..3: which edge slot
    const int db   = (lane & 15) * 4;    // dim base: float4 slice of D=64

    int p0 = row_ptr[row];
    int p1 = row_ptr[row + 1];
    p0 = __builtin_amdgcn_readfirstlane(p0);   // wave-uniform
    p1 = __builtin_amdgcn_readfirstlane(p1);

    float4 acc = make_float4(0.f, 0.f, 0.f, 0.f);

    int k = p0 + sub;
    // Pair-unrolled: two independent 1KB gathers in flight per sub-group.
    while (k + 4 < p1) {
        const int   c0 = edge_col[k];
        const float v0 = edge_val[k];
        const int   c1 = edge_col[k + 4];
        const float v1 = edge_val[k + 4];
        const float4 g0 = *(const float4*)(embeds + (size_t)c0 * GCN_D + db);
        const float4 g1 = *(const float4*)(embeds + (size_t)c1 * GCN_D + db);
        acc.x += v0 * g0.x; acc.y += v0 * g0.y; acc.z += v0 * g0.z; acc.w += v0 * g0.w;
        acc.x += v1 * g1.x; acc.y += v1 * g1.y; acc.z += v1 * g1.z; acc.w += v1 * g1.w;
        k += 8;
    }
    while (k < p1) {
        const int   c = edge_col[k];
        const float v = edge_val[k];
        const float4 g = *(const float4*)(embeds + (size_t)c * GCN_D + db);
        acc.x += v * g.x; acc.y += v * g.y; acc.z += v * g.z; acc.w += v * g.w;
        k += 4;
    }

    // Combine the 4 sub-groups (lanes l, l^16, l^32, l^48 share dims).
    acc.x += __shfl_xor(acc.x, 16); acc.y += __shfl_xor(acc.y, 16);
    acc.z += __shfl_xor(acc.z, 16); acc.w += __shfl_xor(acc.w, 16);
    acc.x += __shfl_xor(acc.x, 32); acc.y += __shfl_xor(acc.y, 32);
    acc.z += __shfl_xor(acc.z, 32); acc.w += __shfl_xor(acc.w, 32);

    if (sub == 0)
        *(float4*)(out + (size_t)row * GCN_D + db) = acc;
}

extern "C" void kernel_launch(void* const* d_in, const int* in_sizes, int n_in,
                              void* d_out, int out_size, void* d_ws, size_t ws_size,
                              hipStream_t stream) {
    const int*   edge_row = (const int*)d_in[0];
    const int*   edge_col = (const int*)d_in[1];
    const float* edge_val = (const float*)d_in[2];
    const float* embeds   = (const float*)d_in[3];
    float*       out      = (float*)d_out;

    const int E = in_sizes[0];
    const int N = out_size / GCN_D;

    int* row_ptr = (int*)d_ws;   // (N+1) ints; d_ws re-poisoned each call,
                                 // build kernel rewrites every entry.

    build_row_ptr_kernel<<<(E + 255) / 256, 256, 0, stream>>>(edge_row, row_ptr, E, N);

    const int blocks = (N + 3) / 4;   // 4 waves (rows) per 256-thread block
    gcn_row_kernel<<<blocks, 256, 0, stream>>>(row_ptr, edge_col, edge_val,
                                               embeds, out, N);
}